// Round 4
// baseline (269.421 us; speedup 1.0000x reference)
//
#include <hip/hip_runtime.h>
#include <math.h>

#define BATCH 16
#define OC_TOT 512
#define HH 128
#define WW 128
#define KK 5
#define NOC 32        // output channels per block
#define BROWS 32      // output rows per block
#define NTHREADS 256
#define HW (HH * WW)

// Block: (batch, 32-row tile, 32 ocs). Thread: 2 rows x 8 cols, loop 32 ocs.
// Taps (25 + bias) per oc in LDS, consumed as float4 broadcasts; input window
// in registers; all arrays statically indexed.
__global__ __launch_bounds__(NTHREADS, 3)
void groupconv_kernel(const float* __restrict__ x,
                      const float* __restrict__ weight,
                      const float* __restrict__ bias,
                      float* __restrict__ out)
{
    __shared__ float sIn[BROWS + 4][WW + 4];  // 36 x 132 input tile (zero halo)
    __shared__ float sW[NOC][28];             // 25 taps + bias + 2 pad

    const int tid = threadIdx.x;
    const int bid = blockIdx.x;
    // grid = BATCH * (HH/BROWS) * (OC_TOT/NOC) = 16*4*16 = 1024
    const int octile = bid & 15;
    const int htile  = (bid >> 4) & 3;
    const int b      = bid >> 6;
    const int h0     = htile * BROWS;
    const int ocbase = octile * NOC;

    // ---- stage input tile (zero halo) ----
    const float* xb = x + b * HW;
    for (int idx = tid; idx < (BROWS + 4) * (WW + 4); idx += NTHREADS) {
        int ry = idx / (WW + 4);
        int cx = idx - ry * (WW + 4);
        int gy = h0 - 2 + ry;
        int gx = cx - 2;
        float v = 0.0f;
        if (gy >= 0 && gy < HH && gx >= 0 && gx < WW)
            v = xb[gy * WW + gx];
        sIn[ry][cx] = v;
    }

    // ---- rotated taps for this block's 32 ocs (d=1 -> plane 0 exactly) ----
    for (int idx = tid; idx < NOC * 25; idx += NTHREADS) {
        int i   = idx / 25;
        int t25 = idx - i * 25;
        int ky  = t25 / 5;
        int kx  = t25 - ky * 5;
        int oc  = ocbase + i;
        int o   = oc >> 4;
        int r   = oc & 15;
        const float* wp = weight + o * 25;
        float theta = 0.39269908169872414f * (float)r;   // 2*pi/16 * r
        float cth = cosf(theta), sth = sinf(theta);
        float ty = ((float)ky + 0.5f) * (2.0f / (float)KK) - 1.0f;
        float tx = ((float)kx + 0.5f) * (2.0f / (float)KK) - 1.0f;
        float xi =  cth * tx + sth * ty;
        float yi = -sth * tx + cth * ty;
        float px = (xi + 1.0f) * ((float)KK * 0.5f) - 0.5f;
        float py = (yi + 1.0f) * ((float)KK * 0.5f) - 0.5f;
        float fx0 = floorf(px), fy0 = floorf(py);
        int   x0 = (int)fx0,  y0 = (int)fy0;
        float wx = px - fx0,  wy = py - fy0;
        float v00 = (y0 >= 0   && y0 < KK   && x0 >= 0   && x0 < KK  ) ? wp[y0 * KK + x0]         : 0.0f;
        float v01 = (y0 >= 0   && y0 < KK   && x0+1 >= 0 && x0+1 < KK) ? wp[y0 * KK + x0 + 1]     : 0.0f;
        float v10 = (y0+1 >= 0 && y0+1 < KK && x0 >= 0   && x0 < KK  ) ? wp[(y0+1) * KK + x0]     : 0.0f;
        float v11 = (y0+1 >= 0 && y0+1 < KK && x0+1 >= 0 && x0+1 < KK) ? wp[(y0+1) * KK + x0 + 1] : 0.0f;
        sW[i][t25] = v00 * (1.0f - wy) * (1.0f - wx)
                   + v01 * (1.0f - wy) * wx
                   + v10 * wy * (1.0f - wx)
                   + v11 * wy * wx;
    }
    for (int i = tid; i < NOC * 3; i += NTHREADS) {
        int oc = i / 3, slot = 25 + (i - oc * 3);
        sW[oc][slot] = (slot == 25) ? bias[(ocbase + oc) >> 4] : 0.0f;
    }
    __syncthreads();

    // ---- thread = 2 rows x 8 cols ----
    const int p    = tid >> 4;          // row pair 0..15
    const int wcol = (tid & 15) * 8;
    const int y0r  = h0 + 2 * p;

    // 6x12 window in registers (18 ds_read_b128, one-time)
    float win[6][12];
#pragma unroll
    for (int r6 = 0; r6 < 6; ++r6) {
        float4 a = *(const float4*)&sIn[2 * p + r6][wcol];
        float4 c = *(const float4*)&sIn[2 * p + r6][wcol + 4];
        float4 e = *(const float4*)&sIn[2 * p + r6][wcol + 8];
        win[r6][0] = a.x; win[r6][1]  = a.y; win[r6][2]  = a.z; win[r6][3]  = a.w;
        win[r6][4] = c.x; win[r6][5]  = c.y; win[r6][6]  = c.z; win[r6][7]  = c.w;
        win[r6][8] = e.x; win[r6][9]  = e.y; win[r6][10] = e.z; win[r6][11] = e.w;
    }

    float* op = out + ((size_t)b * OC_TOT + ocbase) * (size_t)HW
                    + (size_t)y0r * WW + wcol;
    for (int i = 0; i < NOC; ++i) {
        const float4* wrow = (const float4*)&sW[i][0];
        float tap[28];
        *(float4*)&tap[0]  = wrow[0];
        *(float4*)&tap[4]  = wrow[1];
        *(float4*)&tap[8]  = wrow[2];
        *(float4*)&tap[12] = wrow[3];
        *(float4*)&tap[16] = wrow[4];
        *(float4*)&tap[20] = wrow[5];
        *(float4*)&tap[24] = wrow[6];
        float bz = tap[25];
        float a0[8], a1[8];
#pragma unroll
        for (int j = 0; j < 8; ++j) { a0[j] = bz; a1[j] = bz; }
#pragma unroll
        for (int ky = 0; ky < 5; ++ky) {
#pragma unroll
            for (int kx = 0; kx < 5; ++kx) {
                float wv = tap[ky * 5 + kx];
#pragma unroll
                for (int j = 0; j < 8; ++j) {
                    a0[j] = fmaf(win[ky][kx + j],     wv, a0[j]);
                    a1[j] = fmaf(win[ky + 1][kx + j], wv, a1[j]);
                }
            }
        }
        *(float4*)op            = make_float4(a0[0], a0[1], a0[2], a0[3]);
        *(float4*)(op + 4)      = make_float4(a0[4], a0[5], a0[6], a0[7]);
        *(float4*)(op + WW)     = make_float4(a1[0], a1[1], a1[2], a1[3]);
        *(float4*)(op + WW + 4) = make_float4(a1[4], a1[5], a1[6], a1[7]);
        op += HW;
    }
}

extern "C" void kernel_launch(void* const* d_in, const int* in_sizes, int n_in,
                              void* d_out, int out_size, void* d_ws, size_t ws_size,
                              hipStream_t stream)
{
    const float* x      = (const float*)d_in[0];  // (16,1,128,128)
    const float* weight = (const float*)d_in[1];  // (32,1,1,5,5)
    const float* bias   = (const float*)d_in[2];  // (32,)
    float* out = (float*)d_out;                   // (16,32,16,128,128)

    const int nblocks = BATCH * (HH / BROWS) * (OC_TOT / NOC);  // 1024
    groupconv_kernel<<<nblocks, NTHREADS, 0, stream>>>(x, weight, bias, out);
}

// Round 6
// 107.195 us; speedup vs baseline: 2.5134x; 2.5134x over previous
//
#include <hip/hip_runtime.h>
#include <math.h>

#define BATCH 16
#define OC_TOT 512
#define HH 128
#define WW 128
#define KK 5
#define NOC 32      // output channels per block
#define ROWS 16     // output rows per block
#define NTHREADS 256
#define HW (HH * WW)

typedef float floatx4 __attribute__((ext_vector_type(4)));

// Block: (batch, 16-row tile, 32 ocs). Thread: 1 row, two dense 4-col quads
// (cols 4j..4j+3 and 64+4j..64+4j+3) -> every store instruction is fully
// dense across lanes (16 lanes x 16B contiguous = 256B runs). Taps broadcast
// from LDS as float4, consumed immediately; stores are nontemporal.
__global__ __launch_bounds__(NTHREADS, 2)
void groupconv_kernel(const float* __restrict__ x,
                      const float* __restrict__ weight,
                      const float* __restrict__ bias,
                      float* __restrict__ out)
{
    __shared__ float sIn[ROWS + 4][WW + 4];   // 20 x 132 input tile (zero halo)
    __shared__ float sW[NOC][28];             // 25 taps + bias + 2 pad

    const int tid = threadIdx.x;
    const int bid = blockIdx.x;
    // grid = BATCH * (HH/ROWS) * (OC_TOT/NOC) = 16*8*16 = 2048
    const int octile = bid & 15;
    const int htile  = (bid >> 4) & 7;
    const int b      = bid >> 7;
    const int h0     = htile * ROWS;
    const int ocbase = octile * NOC;

    // ---- stage input tile (zero halo) ----
    const float* xb = x + b * HW;
    for (int idx = tid; idx < (ROWS + 4) * (WW + 4); idx += NTHREADS) {
        int ry = idx / (WW + 4);
        int cx = idx - ry * (WW + 4);
        int gy = h0 - 2 + ry;
        int gx = cx - 2;
        float v = 0.0f;
        if (gy >= 0 && gy < HH && gx >= 0 && gx < WW)
            v = xb[gy * WW + gx];
        sIn[ry][cx] = v;
    }

    // ---- rotated taps for this block's 32 ocs (d=1 -> plane 0 exactly) ----
    for (int idx = tid; idx < NOC * 25; idx += NTHREADS) {
        int i   = idx / 25;
        int t25 = idx - i * 25;
        int ky  = t25 / 5;
        int kx  = t25 - ky * 5;
        int oc  = ocbase + i;
        int o   = oc >> 4;
        int r   = oc & 15;
        const float* wp = weight + o * 25;
        float theta = 0.39269908169872414f * (float)r;   // 2*pi/16 * r
        float cth = cosf(theta), sth = sinf(theta);
        float ty = ((float)ky + 0.5f) * (2.0f / (float)KK) - 1.0f;
        float tx = ((float)kx + 0.5f) * (2.0f / (float)KK) - 1.0f;
        float xi =  cth * tx + sth * ty;
        float yi = -sth * tx + cth * ty;
        float px = (xi + 1.0f) * ((float)KK * 0.5f) - 0.5f;
        float py = (yi + 1.0f) * ((float)KK * 0.5f) - 0.5f;
        float fx0 = floorf(px), fy0 = floorf(py);
        int   x0 = (int)fx0,  y0 = (int)fy0;
        float wx = px - fx0,  wy = py - fy0;
        float v00 = (y0 >= 0   && y0 < KK   && x0 >= 0   && x0 < KK  ) ? wp[y0 * KK + x0]         : 0.0f;
        float v01 = (y0 >= 0   && y0 < KK   && x0+1 >= 0 && x0+1 < KK) ? wp[y0 * KK + x0 + 1]     : 0.0f;
        float v10 = (y0+1 >= 0 && y0+1 < KK && x0 >= 0   && x0 < KK  ) ? wp[(y0+1) * KK + x0]     : 0.0f;
        float v11 = (y0+1 >= 0 && y0+1 < KK && x0+1 >= 0 && x0+1 < KK) ? wp[(y0+1) * KK + x0 + 1] : 0.0f;
        sW[i][t25] = v00 * (1.0f - wy) * (1.0f - wx)
                   + v01 * (1.0f - wy) * wx
                   + v10 * wy * (1.0f - wx)
                   + v11 * wy * wx;
    }
    for (int i = tid; i < NOC * 3; i += NTHREADS) {
        int oc = i / 3, slot = 25 + (i - oc * 3);
        sW[oc][slot] = (slot == 25) ? bias[(ocbase + oc) >> 4] : 0.0f;
    }
    __syncthreads();

    // ---- thread = 1 row, cols [4j,4j+3] and [64+4j,64+4j+3] ----
    const int row = tid >> 4;           // 0..15
    const int j4  = (tid & 15) * 4;     // 0,4,...,60
    const int h   = h0 + row;

    // two 5x8 windows in registers (20 ds_read_b128, one-time, 2-way free)
    float winA[5][8], winB[5][8];
#pragma unroll
    for (int r5 = 0; r5 < 5; ++r5) {
        float4 a = *(const float4*)&sIn[row + r5][j4];
        float4 c = *(const float4*)&sIn[row + r5][j4 + 4];
        float4 e = *(const float4*)&sIn[row + r5][64 + j4];
        float4 f = *(const float4*)&sIn[row + r5][64 + j4 + 4];
        winA[r5][0] = a.x; winA[r5][1] = a.y; winA[r5][2] = a.z; winA[r5][3] = a.w;
        winA[r5][4] = c.x; winA[r5][5] = c.y; winA[r5][6] = c.z; winA[r5][7] = c.w;
        winB[r5][0] = e.x; winB[r5][1] = e.y; winB[r5][2] = e.z; winB[r5][3] = e.w;
        winB[r5][4] = f.x; winB[r5][5] = f.y; winB[r5][6] = f.z; winB[r5][7] = f.w;
    }

    float* op = out + ((size_t)b * OC_TOT + ocbase) * (size_t)HW
                    + (size_t)h * WW + j4;

#define APPLY(W, KY, KX)                                    \
    a0 = fmaf(winA[KY][(KX)],     (W), a0);                 \
    a1 = fmaf(winA[KY][(KX) + 1], (W), a1);                 \
    a2 = fmaf(winA[KY][(KX) + 2], (W), a2);                 \
    a3 = fmaf(winA[KY][(KX) + 3], (W), a3);                 \
    b0 = fmaf(winB[KY][(KX)],     (W), b0);                 \
    b1 = fmaf(winB[KY][(KX) + 1], (W), b1);                 \
    b2 = fmaf(winB[KY][(KX) + 2], (W), b2);                 \
    b3 = fmaf(winB[KY][(KX) + 3], (W), b3);

    for (int i = 0; i < NOC; ++i) {
        const float4* wrow = (const float4*)&sW[i][0];
        float4 q6 = wrow[6];                 // {tap24, bias, 0, 0}
        float bz = q6.y;
        float a0 = bz, a1 = bz, a2 = bz, a3 = bz;
        float b0 = bz, b1 = bz, b2 = bz, b3 = bz;
        float4 q;
        q = wrow[0];  APPLY(q.x,0,0) APPLY(q.y,0,1) APPLY(q.z,0,2) APPLY(q.w,0,3)
        q = wrow[1];  APPLY(q.x,0,4) APPLY(q.y,1,0) APPLY(q.z,1,1) APPLY(q.w,1,2)
        q = wrow[2];  APPLY(q.x,1,3) APPLY(q.y,1,4) APPLY(q.z,2,0) APPLY(q.w,2,1)
        q = wrow[3];  APPLY(q.x,2,2) APPLY(q.y,2,3) APPLY(q.z,2,4) APPLY(q.w,3,0)
        q = wrow[4];  APPLY(q.x,3,1) APPLY(q.y,3,2) APPLY(q.z,3,3) APPLY(q.w,3,4)
        q = wrow[5];  APPLY(q.x,4,0) APPLY(q.y,4,1) APPLY(q.z,4,2) APPLY(q.w,4,3)
        APPLY(q6.x,4,4)

        floatx4 va = {a0, a1, a2, a3};
        floatx4 vb = {b0, b1, b2, b3};
        __builtin_nontemporal_store(va, (floatx4*)op);
        __builtin_nontemporal_store(vb, (floatx4*)(op + 64));
        op += HW;
    }
#undef APPLY
}

extern "C" void kernel_launch(void* const* d_in, const int* in_sizes, int n_in,
                              void* d_out, int out_size, void* d_ws, size_t ws_size,
                              hipStream_t stream)
{
    const float* x      = (const float*)d_in[0];  // (16,1,128,128)
    const float* weight = (const float*)d_in[1];  // (32,1,1,5,5)
    const float* bias   = (const float*)d_in[2];  // (32,)
    float* out = (float*)d_out;                   // (16,32,16,128,128)

    const int nblocks = BATCH * (HH / ROWS) * (OC_TOT / NOC);  // 2048
    groupconv_kernel<<<nblocks, NTHREADS, 0, stream>>>(x, weight, bias, out);
}